// Round 1
// baseline (4381.385 us; speedup 1.0000x reference)
//
#include <hip/hip_runtime.h>
#include <math.h>

// Problem: B=16, M=1024, N=1024 fp32; 20 ADMM iterations.
// RHO=1, LAMBD=0.1, ALPHA=0.5 -> threshold = 0.05, scale-const = 0.05.
#define NB 16
#define NM 1024
#define NN 1024
#define NROWS (NB * NM)      // 16384 rows (softmax rows, length NN)
#define TPB 256
#define RPB 8                // rows per block
#define NGRID (NROWS / RPB)  // 2048 blocks

#define MINV 1e-40f
#define THR  0.05f   // ALPHA*LAMBD/RHO
#define SCLC 0.05f   // (1-ALPHA)*LAMBD/RHO
#define EPSL 1e-10f

__device__ __forceinline__ float wred_max(float v) {
#pragma unroll
  for (int o = 32; o > 0; o >>= 1) v = fmaxf(v, __shfl_xor(v, o, 64));
  return v;
}
__device__ __forceinline__ float wred_sum(float v) {
#pragma unroll
  for (int o = 32; o > 0; o >>= 1) v += __shfl_xor(v, o, 64);
  return v;
}
// 256-thread block reductions (4 waves), broadcast result to all threads.
__device__ __forceinline__ float bred_max(float v, float* red) {
  v = wred_max(v);
  __syncthreads();  // protect red from previous reduction's readers
  if ((threadIdx.x & 63) == 0) red[threadIdx.x >> 6] = v;
  __syncthreads();
  return fmaxf(fmaxf(red[0], red[1]), fmaxf(red[2], red[3]));
}
__device__ __forceinline__ float bred_sum(float v, float* red) {
  v = wred_sum(v);
  __syncthreads();
  if ((threadIdx.x & 63) == 0) red[threadIdx.x >> 6] = v;
  __syncthreads();
  return (red[0] + red[1]) + (red[2] + red[3]);
}
__device__ __forceinline__ float softthr(float x) {
  return copysignf(fmaxf(fabsf(x) - THR, 0.0f), x);
}

// Iteration 1: X = R_0, Z = 0  ->  tmp = (log R0' + log R0')/2 = log R0'.
// Computes R_1 = softmax(log R0') and accumulates colsum of softthr(R_1)^2.
__global__ __launch_bounds__(TPB) void k_start(const float* __restrict__ R0,
                                               float* __restrict__ R,
                                               float* __restrict__ colsum) {
  __shared__ float red[4];
  const int c0 = threadIdx.x * 4;
  float acc[4] = {0.f, 0.f, 0.f, 0.f};
  for (int rr = 0; rr < RPB; ++rr) {
    const size_t row = (size_t)blockIdx.x * RPB + rr;
    const size_t off = row * NN + c0;
    const float4 r0 = *(const float4*)(R0 + off);
    float t[4];
    t[0] = logf(r0.x == 0.f ? MINV : r0.x);
    t[1] = logf(r0.y == 0.f ? MINV : r0.y);
    t[2] = logf(r0.z == 0.f ? MINV : r0.z);
    t[3] = logf(r0.w == 0.f ? MINV : r0.w);
    const float mx = bred_max(fmaxf(fmaxf(t[0], t[1]), fmaxf(t[2], t[3])), red);
    float p[4];
#pragma unroll
    for (int j = 0; j < 4; ++j) p[j] = expf(t[j] - mx);
    const float sum = bred_sum((p[0] + p[1]) + (p[2] + p[3]), red);
    const float inv = 1.0f / sum;
    float rn[4];
#pragma unroll
    for (int j = 0; j < 4; ++j) rn[j] = p[j] * inv;
    *(float4*)(R + off) = make_float4(rn[0], rn[1], rn[2], rn[3]);
    // s_td = softthr(R + Z) with Z = 0
#pragma unroll
    for (int j = 0; j < 4; ++j) {
      const float s = softthr(rn[j]);
      acc[j] += s * s;
    }
  }
#pragma unroll
  for (int j = 0; j < 4; ++j) atomicAdd(&colsum[c0 + j], acc[j]);
}

// colsum -> scale, and reset colsum for the next accumulation. 1024 threads.
__global__ void k_finalize(float* __restrict__ colsum, float* __restrict__ scale) {
  const int i = blockIdx.x * blockDim.x + threadIdx.x;
  const float cn = sqrtf(colsum[i]);
  scale[i] = fmaxf(1.0f - SCLC / (cn + EPSL), 0.0f);
  colsum[i] = 0.0f;
}

// Fused: finish iteration t (X_t, Z_t) + start iteration t+1 (R_{t+1}) +
// accumulate colsums for iteration t+1's X. X is never materialized.
__global__ __launch_bounds__(TPB) void k_ab(const float* __restrict__ R0,
                                            float* __restrict__ R,
                                            float* __restrict__ Z,
                                            const float* __restrict__ scale,
                                            float* __restrict__ colsum,
                                            int z_zero, int accum) {
  __shared__ float red[4];
  const int c0 = threadIdx.x * 4;
  const float4 scv = *(const float4*)(scale + c0);
  const float sc[4] = {scv.x, scv.y, scv.z, scv.w};
  float acc[4] = {0.f, 0.f, 0.f, 0.f};
  for (int rr = 0; rr < RPB; ++rr) {
    const size_t row = (size_t)blockIdx.x * RPB + rr;
    const size_t off = row * NN + c0;
    const float4 rv4 = *(const float4*)(R + off);
    const float rv[4] = {rv4.x, rv4.y, rv4.z, rv4.w};
    float zv[4];
    if (z_zero) {
      zv[0] = zv[1] = zv[2] = zv[3] = 0.f;
    } else {
      const float4 z4 = *(const float4*)(Z + off);
      zv[0] = z4.x; zv[1] = z4.y; zv[2] = z4.z; zv[3] = z4.w;
    }
    const float4 r04 = *(const float4*)(R0 + off);
    const float r0[4] = {r04.x, r04.y, r04.z, r04.w};

    float t[4], zn[4];
#pragma unroll
    for (int j = 0; j < 4; ++j) {
      const float x = rv[j] + zv[j];          // R + Z/RHO, RHO=1
      const float s = softthr(x);
      const float X = sc[j] * s;              // X_t
      zn[j] = zv[j] + (rv[j] - X);            // Z_t
      const float l0 = logf(r0[j] == 0.f ? MINV : r0[j]);
      const float lX = logf(X == 0.f ? MINV : X);
      t[j] = 0.5f * (l0 + lX - zn[j]);        // (log R0' + RHO log X' - Z)/(1+RHO)
    }
    const float mx = bred_max(fmaxf(fmaxf(t[0], t[1]), fmaxf(t[2], t[3])), red);
    float p[4];
#pragma unroll
    for (int j = 0; j < 4; ++j) p[j] = expf(t[j] - mx);
    const float sum = bred_sum((p[0] + p[1]) + (p[2] + p[3]), red);
    const float inv = 1.0f / sum;
    float rn[4];
#pragma unroll
    for (int j = 0; j < 4; ++j) rn[j] = p[j] * inv;  // R_{t+1}
    *(float4*)(R + off) = make_float4(rn[0], rn[1], rn[2], rn[3]);
    *(float4*)(Z + off) = make_float4(zn[0], zn[1], zn[2], zn[3]);
    if (accum) {
#pragma unroll
      for (int j = 0; j < 4; ++j) {
        const float s = softthr(rn[j] + zn[j]);  // next iteration's s_td
        acc[j] += s * s;
      }
    }
  }
  if (accum) {
#pragma unroll
    for (int j = 0; j < 4; ++j) atomicAdd(&colsum[c0 + j], acc[j]);
  }
}

extern "C" void kernel_launch(void* const* d_in, const int* in_sizes, int n_in,
                              void* d_out, int out_size, void* d_ws, size_t ws_size,
                              hipStream_t stream) {
  (void)in_sizes; (void)n_in; (void)out_size; (void)ws_size;
  const float* R0 = (const float*)d_in[0];
  float* R = (float*)d_out;                 // R lives in d_out; final R_20 lands there
  float* Z = (float*)d_ws;                  // 64 MB
  float* colsum = (float*)((char*)d_ws + (size_t)NROWS * NN * sizeof(float));
  float* scale = colsum + NN;

  hipMemsetAsync(colsum, 0, NN * sizeof(float), stream);
  k_start<<<NGRID, TPB, 0, stream>>>(R0, R, colsum);
  for (int it = 1; it < 20; ++it) {
    k_finalize<<<NN / TPB, TPB, 0, stream>>>(colsum, scale);
    k_ab<<<NGRID, TPB, 0, stream>>>(R0, R, Z, scale, colsum,
                                    (it == 1) ? 1 : 0, (it < 19) ? 1 : 0);
  }
}

// Round 2
// 2596.788 us; speedup vs baseline: 1.6872x; 1.6872x over previous
//
#include <hip/hip_runtime.h>
#include <math.h>

// Problem: B=16, M=1024, N=1024 fp32; 20 ADMM iterations.
// RHO=1, LAMBD=0.1, ALPHA=0.5 -> threshold = 0.05, scale-const = 0.05.
#define NB 16
#define NM 1024
#define NN 1024
#define NROWS (NB * NM)      // 16384 softmax rows of length 1024
#define TPB 256              // 4 waves/block
#define RPW 4                // rows per wave
#define NGRID (NROWS / (4 * RPW))  // 1024 blocks

#define MINV 1e-40f
#define THR  0.05f   // ALPHA*LAMBD/RHO
#define SCLC 0.05f   // (1-ALPHA)*LAMBD/RHO
#define EPSL 1e-10f

// Wave-level (64-lane) reductions — no LDS, no barriers.
__device__ __forceinline__ float wred_max(float v) {
#pragma unroll
  for (int o = 32; o > 0; o >>= 1) v = fmaxf(v, __shfl_xor(v, o, 64));
  return v;
}
__device__ __forceinline__ float wred_sum(float v) {
#pragma unroll
  for (int o = 32; o > 0; o >>= 1) v += __shfl_xor(v, o, 64);
  return v;
}
__device__ __forceinline__ float softthr(float x) {
  return copysignf(fmaxf(fabsf(x) - THR, 0.0f), x);
}

// One row per wave: lane L handles columns {c*256 + L*4 + j}, c,j in 0..3.
// Loads are float4, fully coalesced (1 KiB/instruction per wave).

// Iteration 1: X = R_0, Z = 0 -> tmp = log R0'. R_1 = softmax(log R0').
// Accumulates colsum of softthr(R_1)^2 for iteration 2's scale.
__global__ __launch_bounds__(TPB) void k_start(const float* __restrict__ R0,
                                               float* __restrict__ R,
                                               float* __restrict__ colsum) {
  __shared__ float lds[4 * NN];  // 16 KB: per-wave colsum partials
  const int lane = threadIdx.x & 63;
  const int wv = threadIdx.x >> 6;
  const size_t wid = (size_t)blockIdx.x * 4 + wv;
  float acc[4][4] = {};
  for (int rr = 0; rr < RPW; ++rr) {
    const size_t base = (wid * RPW + rr) * NN + (size_t)lane * 4;
    float t[4][4];
    float mloc = -3.4e38f;
#pragma unroll
    for (int c = 0; c < 4; ++c) {
      const float4 r4 = *(const float4*)(R0 + base + c * 256);
      const float r0[4] = {r4.x, r4.y, r4.z, r4.w};
#pragma unroll
      for (int j = 0; j < 4; ++j) {
        t[c][j] = logf(r0[j] == 0.f ? MINV : r0[j]);
        mloc = fmaxf(mloc, t[c][j]);
      }
    }
    const float mx = wred_max(mloc);
    float sloc = 0.f;
#pragma unroll
    for (int c = 0; c < 4; ++c)
#pragma unroll
      for (int j = 0; j < 4; ++j) {
        t[c][j] = expf(t[c][j] - mx);
        sloc += t[c][j];
      }
    const float inv = 1.0f / wred_sum(sloc);
#pragma unroll
    for (int c = 0; c < 4; ++c) {
      float rn[4];
#pragma unroll
      for (int j = 0; j < 4; ++j) {
        rn[j] = t[c][j] * inv;
        const float s = softthr(rn[j]);  // Z = 0
        acc[c][j] += s * s;
      }
      *(float4*)(R + base + c * 256) = make_float4(rn[0], rn[1], rn[2], rn[3]);
    }
  }
#pragma unroll
  for (int c = 0; c < 4; ++c)
    *(float4*)(&lds[wv * NN + c * 256 + lane * 4]) =
        make_float4(acc[c][0], acc[c][1], acc[c][2], acc[c][3]);
  __syncthreads();
  const int col = threadIdx.x * 4;
  float4 s0 = *(float4*)(&lds[0 * NN + col]);
  float4 s1 = *(float4*)(&lds[1 * NN + col]);
  float4 s2 = *(float4*)(&lds[2 * NN + col]);
  float4 s3 = *(float4*)(&lds[3 * NN + col]);
  atomicAdd(&colsum[col + 0], (s0.x + s1.x) + (s2.x + s3.x));
  atomicAdd(&colsum[col + 1], (s0.y + s1.y) + (s2.y + s3.y));
  atomicAdd(&colsum[col + 2], (s0.z + s1.z) + (s2.z + s3.z));
  atomicAdd(&colsum[col + 3], (s0.w + s1.w) + (s2.w + s3.w));
}

// colsum -> scale, reset colsum for the next accumulation. 1024 threads.
__global__ void k_finalize(float* __restrict__ colsum, float* __restrict__ scale) {
  const int i = blockIdx.x * blockDim.x + threadIdx.x;
  const float cn = sqrtf(colsum[i]);
  scale[i] = fmaxf(1.0f - SCLC / (cn + EPSL), 0.0f);
  colsum[i] = 0.0f;
}

// Fused: finish iteration t (X_t, Z_t) + compute R_{t+1} + accumulate colsums
// for iteration t+1's X. X is never materialized. Barrier-free row loop.
__global__ __launch_bounds__(TPB) void k_ab(const float* __restrict__ R0,
                                            float* __restrict__ R,
                                            float* __restrict__ Z,
                                            const float* __restrict__ scale,
                                            float* __restrict__ colsum,
                                            int z_zero, int accum) {
  __shared__ float lds[4 * NN];  // 16 KB
  const int lane = threadIdx.x & 63;
  const int wv = threadIdx.x >> 6;
  const size_t wid = (size_t)blockIdx.x * 4 + wv;
  float sc[4][4];
#pragma unroll
  for (int c = 0; c < 4; ++c) {
    const float4 s4 = *(const float4*)(scale + c * 256 + lane * 4);
    sc[c][0] = s4.x; sc[c][1] = s4.y; sc[c][2] = s4.z; sc[c][3] = s4.w;
  }
  float acc[4][4] = {};
  for (int rr = 0; rr < RPW; ++rr) {
    const size_t base = (wid * RPW + rr) * NN + (size_t)lane * 4;
    float t[4][4], zn[4][4];
    float mloc = -3.4e38f;
#pragma unroll
    for (int c = 0; c < 4; ++c) {
      const float4 rv4 = *(const float4*)(R + base + c * 256);
      const float4 r04 = *(const float4*)(R0 + base + c * 256);
      const float rv[4] = {rv4.x, rv4.y, rv4.z, rv4.w};
      const float r0[4] = {r04.x, r04.y, r04.z, r04.w};
      float zv[4];
      if (z_zero) {
        zv[0] = zv[1] = zv[2] = zv[3] = 0.f;
      } else {
        const float4 z4 = *(const float4*)(Z + base + c * 256);
        zv[0] = z4.x; zv[1] = z4.y; zv[2] = z4.z; zv[3] = z4.w;
      }
#pragma unroll
      for (int j = 0; j < 4; ++j) {
        const float x = rv[j] + zv[j];          // R + Z/RHO, RHO=1
        const float s = softthr(x);
        const float X = sc[c][j] * s;           // X_t
        zn[c][j] = zv[j] + (rv[j] - X);         // Z_t
        const float l0 = logf(r0[j] == 0.f ? MINV : r0[j]);
        const float lX = logf(X == 0.f ? MINV : X);
        t[c][j] = 0.5f * (l0 + lX - zn[c][j]);  // (log R0' + log X' - Z)/2
        mloc = fmaxf(mloc, t[c][j]);
      }
    }
    const float mx = wred_max(mloc);
    float sloc = 0.f;
#pragma unroll
    for (int c = 0; c < 4; ++c)
#pragma unroll
      for (int j = 0; j < 4; ++j) {
        t[c][j] = expf(t[c][j] - mx);
        sloc += t[c][j];
      }
    const float inv = 1.0f / wred_sum(sloc);
#pragma unroll
    for (int c = 0; c < 4; ++c) {
      float rn[4];
#pragma unroll
      for (int j = 0; j < 4; ++j) rn[j] = t[c][j] * inv;  // R_{t+1}
      *(float4*)(R + base + c * 256) = make_float4(rn[0], rn[1], rn[2], rn[3]);
      *(float4*)(Z + base + c * 256) =
          make_float4(zn[c][0], zn[c][1], zn[c][2], zn[c][3]);
      if (accum) {
#pragma unroll
        for (int j = 0; j < 4; ++j) {
          const float s = softthr(rn[j] + zn[c][j]);  // next iter's s_td
          acc[c][j] += s * s;
        }
      }
    }
  }
  if (accum) {
#pragma unroll
    for (int c = 0; c < 4; ++c)
      *(float4*)(&lds[wv * NN + c * 256 + lane * 4]) =
          make_float4(acc[c][0], acc[c][1], acc[c][2], acc[c][3]);
    __syncthreads();
    const int col = threadIdx.x * 4;
    float4 s0 = *(float4*)(&lds[0 * NN + col]);
    float4 s1 = *(float4*)(&lds[1 * NN + col]);
    float4 s2 = *(float4*)(&lds[2 * NN + col]);
    float4 s3 = *(float4*)(&lds[3 * NN + col]);
    atomicAdd(&colsum[col + 0], (s0.x + s1.x) + (s2.x + s3.x));
    atomicAdd(&colsum[col + 1], (s0.y + s1.y) + (s2.y + s3.y));
    atomicAdd(&colsum[col + 2], (s0.z + s1.z) + (s2.z + s3.z));
    atomicAdd(&colsum[col + 3], (s0.w + s1.w) + (s2.w + s3.w));
  }
}

extern "C" void kernel_launch(void* const* d_in, const int* in_sizes, int n_in,
                              void* d_out, int out_size, void* d_ws, size_t ws_size,
                              hipStream_t stream) {
  (void)in_sizes; (void)n_in; (void)out_size; (void)ws_size;
  const float* R0 = (const float*)d_in[0];
  float* R = (float*)d_out;                 // final R_20 lands in d_out
  float* Z = (float*)d_ws;                  // 64 MB
  float* colsum = (float*)((char*)d_ws + (size_t)NROWS * NN * sizeof(float));
  float* scale = colsum + NN;

  hipMemsetAsync(colsum, 0, NN * sizeof(float), stream);
  k_start<<<NGRID, TPB, 0, stream>>>(R0, R, colsum);
  for (int it = 1; it < 20; ++it) {
    k_finalize<<<NN / TPB, TPB, 0, stream>>>(colsum, scale);
    k_ab<<<NGRID, TPB, 0, stream>>>(R0, R, Z, scale, colsum,
                                    (it == 1) ? 1 : 0, (it < 19) ? 1 : 0);
  }
}